// Round 1
// baseline (711.279 us; speedup 1.0000x reference)
//
#include <hip/hip_runtime.h>

typedef unsigned long long u64;

#define G_    4096
#define BATCH 16
#define NPTS  16384

// ---------------- ws layout (bytes) ----------------
// keys  u64 [16][4096]  @ 0        (524288)
// base  i32 [16][4096]  @ 524288   (262144)
// nv    i32 [16][4096]  @ 786432   (262144)
// rem   i32 [16]        @ 1048576  (64)
// pc    i32 [16][16384] @ 1048832  (1048576)
// w1t   f32 [72][256]   @ 2097408  (73728)   (rows 66..71 = pad, never computed on)
// w2t   f32 [256][256]  @ 2171136  (262144)
// w3t   f32 [256][4]    @ 2433280  (4096)
// total 2437376 bytes

// ---- transpose weights for coalesced chunk staging ----
__global__ void kT(const float* __restrict__ W1, const float* __restrict__ W2,
                   const float* __restrict__ W3,
                   float* __restrict__ w1t, float* __restrict__ w2t, float* __restrict__ w3t){
  int k = blockIdx.x, r = threadIdx.x;
  w2t[k*256 + r] = W2[r*256 + k];
  if (k < 66) w1t[k*256 + r] = W1[r*66 + k];
  if (k == 0){
    w3t[r*4 + 0] = W3[0*256 + r];
    w3t[r*4 + 1] = W3[1*256 + r];
    w3t[r*4 + 2] = W3[2*256 + r];
    w3t[r*4 + 3] = 0.f;
  }
}

// ---- per-batch: S (correctly-rounded f32 sum), base, frac keys, rem ----
__global__ void kA(const float* __restrict__ dens, u64* __restrict__ keys,
                   int* __restrict__ base, int* __restrict__ rem){
  __shared__ double sred[256];
  __shared__ int    ired[256];
  __shared__ float  Sf;
  const int b = blockIdx.x, t = threadIdx.x;
  const float* d = dens + b*G_;
  double s = 0.0;
  for (int j = 0; j < 16; ++j) s += (double)d[t + 256*j];
  sred[t] = s; __syncthreads();
  for (int off = 128; off > 0; off >>= 1){
    if (t < off) sred[t] += sred[t + off];
    __syncthreads();
  }
  if (t == 0) Sf = (float)sred[0];
  __syncthreads();
  const float S = Sf;
  int bs = 0;
  for (int j = 0; j < 16; ++j){
    int i = t + 256*j;
    float p  = d[i] / S;          // mirrors ref: p = dens / sum
    float sc = p * 16384.0f;      // exact (×2^14)
    float fl = floorf(sc);
    float fr = sc - fl;           // exact
    int bi = (int)fl;
    keys[b*G_ + i] = ((u64)__float_as_uint(fr) << 12) | (u64)(4095 - i);
    base[b*G_ + i] = bi;
    bs += bi;
  }
  ired[t] = bs; __syncthreads();
  for (int off = 128; off > 0; off >>= 1){
    if (t < off) ired[t] += ired[t + off];
    __syncthreads();
  }
  if (t == 0) rem[b] = 16384 - ired[0];
}

// ---- rank by counting: n = base + (rank < rem) ----
__global__ void kB(const u64* __restrict__ keys, const int* __restrict__ base,
                   const int* __restrict__ rem, int* __restrict__ nv){
  __shared__ u64 kb[4096];
  const int b = blockIdx.y, slice = blockIdx.x, t = threadIdx.x;
  const u64* kk = keys + b*G_;
  for (int j = t; j < 4096; j += 256) kb[j] = kk[j];
  __syncthreads();
  const int i = slice*256 + t;
  const u64 K = kb[i];
  int cnt = 0;
  #pragma unroll 8
  for (int j = 0; j < 4096; ++j) cnt += (kb[j] > K) ? 1 : 0;
  nv[b*G_ + i] = base[b*G_ + i] + ((cnt < rem[b]) ? 1 : 0);
}

// ---- prefix sum + expand to per-point cell ids (ascending, matches jnp.repeat) ----
__global__ void kC(const int* __restrict__ nv, int* __restrict__ pc){
  __shared__ int psum[256];
  const int b = blockIdx.x, t = threadIdx.x;
  const int* n = nv + b*G_;
  int loc[16]; int s = 0;
  #pragma unroll
  for (int j = 0; j < 16; ++j){ loc[j] = n[t*16 + j]; s += loc[j]; }
  psum[t] = s; __syncthreads();
  for (int off = 1; off < 256; off <<= 1){
    int v = (t >= off) ? psum[t - off] : 0;
    __syncthreads();
    psum[t] += v;
    __syncthreads();
  }
  int off0 = psum[t] - s;   // exclusive prefix
  int* o = pc + b*NPTS;
  #pragma unroll
  for (int j = 0; j < 16; ++j){
    int c = t*16 + j;
    for (int r = 0; r < loc[j]; ++r) o[off0++] = c;
  }
}

// ---- GEMM micro-kernel: 4 rows x 8 points per thread, K-chunk from LDS ----
template<int KW>
__device__ inline void gemm_chunk(const float* __restrict__ wchunk,
                                  const float* __restrict__ inbuf,
                                  int k0, int rg, int pg, float (&acc)[4][8]){
  #pragma unroll
  for (int kk = 0; kk < KW; ++kk){
    const float4 w4 = *(const float4*)&wchunk[kk*256 + rg*4];
    const float4 x0 = *(const float4*)&inbuf[(k0+kk)*32 + pg*8];
    const float4 x1 = *(const float4*)&inbuf[(k0+kk)*32 + pg*8 + 4];
    const float wv[4] = {w4.x, w4.y, w4.z, w4.w};
    const float xv[8] = {x0.x, x0.y, x0.z, x0.w, x1.x, x1.y, x1.z, x1.w};
    #pragma unroll
    for (int a = 0; a < 4; ++a)
      #pragma unroll
      for (int q = 0; q < 8; ++q)
        acc[a][q] += wv[a] * xv[q];
  }
}

// ---- the MLP: 32 points/block, rows 256, f32 VALU ----
__global__ __launch_bounds__(256, 2) void kD(
    const float* __restrict__ x, const float* __restrict__ noise,
    const float* __restrict__ w1t, const float* __restrict__ w2t, const float* __restrict__ w3t,
    const float* __restrict__ b1, const float* __restrict__ b2, const float* __restrict__ b3,
    const int* __restrict__ pc, float* __restrict__ out)
{
  __shared__ float bufA[8192];      // 32 KB: [k][32] layer input / h2
  __shared__ float bufB[8192];      // 32 KB: h1
  __shared__ float wt[2][2048];     // 16 KB: double-buffered W chunk [8][256]
  const int b   = blockIdx.y;
  const int p0  = blockIdx.x * 32;
  const int tid = threadIdx.x;
  const int rg  = tid >> 2, pg = tid & 3;
  int* cells = (int*)&bufA[2112];   // overlay at row 66 (unused by layer-1 input)

  if (tid < 32) cells[tid] = pc[b*NPTS + p0 + tid];
  if (tid >= 64 && tid < 128){
    int rr = (tid - 64) >> 5, p = tid & 31;
    bufA[(64 + rr)*32 + p] = noise[b*2*NPTS + rr*NPTS + p0 + p] * 2.0f - 1.0f;
  }
  __syncthreads();
  const int mycell = cells[tid >> 3];   // save before bufA is overwritten
  {
    const float* xb = x + b*64*G_;
    #pragma unroll
    for (int j = 0; j < 8; ++j){
      int idx = tid + j*256;
      int c = idx >> 5, p = idx & 31;
      bufA[c*32 + p] = xb[c*G_ + cells[p]];
    }
  }

  float acc[4][8];
  #pragma unroll
  for (int a = 0; a < 4; ++a)
    #pragma unroll
    for (int q = 0; q < 8; ++q) acc[a][q] = 0.f;

  float4 s0, s1;

  // -------- layer 1: K=66 (9 chunks, last = 2 rows) --------
  s0 = *(const float4*)(w1t + tid*8);
  s1 = *(const float4*)(w1t + tid*8 + 4);
  *(float4*)&wt[0][tid*8]     = s0;
  *(float4*)&wt[0][tid*8 + 4] = s1;
  #pragma unroll 1
  for (int c = 0; c < 9; ++c){
    if (c < 8){
      s0 = *(const float4*)(w1t + (c+1)*2048 + tid*8);
      s1 = *(const float4*)(w1t + (c+1)*2048 + tid*8 + 4);
    }
    __syncthreads();
    if (c < 8) gemm_chunk<8>(&wt[c&1][0], bufA, c*8, rg, pg, acc);
    else       gemm_chunk<2>(&wt[c&1][0], bufA, c*8, rg, pg, acc);
    if (c < 8){
      *(float4*)&wt[(c+1)&1][tid*8]     = s0;
      *(float4*)&wt[(c+1)&1][tid*8 + 4] = s1;
    }
  }

  // epilogue L1 -> bufB; prefetch L2 chunk0
  s0 = *(const float4*)(w2t + tid*8);
  s1 = *(const float4*)(w2t + tid*8 + 4);
  {
    const float4 bq = *(const float4*)(b1 + rg*4);
    const float ba[4] = {bq.x, bq.y, bq.z, bq.w};
    #pragma unroll
    for (int a = 0; a < 4; ++a){
      float4 v0, v1;
      v0.x = fmaxf(acc[a][0] + ba[a], 0.f); v0.y = fmaxf(acc[a][1] + ba[a], 0.f);
      v0.z = fmaxf(acc[a][2] + ba[a], 0.f); v0.w = fmaxf(acc[a][3] + ba[a], 0.f);
      v1.x = fmaxf(acc[a][4] + ba[a], 0.f); v1.y = fmaxf(acc[a][5] + ba[a], 0.f);
      v1.z = fmaxf(acc[a][6] + ba[a], 0.f); v1.w = fmaxf(acc[a][7] + ba[a], 0.f);
      *(float4*)&bufB[(rg*4 + a)*32 + pg*8]     = v0;
      *(float4*)&bufB[(rg*4 + a)*32 + pg*8 + 4] = v1;
      #pragma unroll
      for (int q = 0; q < 8; ++q) acc[a][q] = 0.f;
    }
  }
  __syncthreads();                 // everyone done with wt[0] (L1 tail) + bufB visible
  *(float4*)&wt[0][tid*8]     = s0;
  *(float4*)&wt[0][tid*8 + 4] = s1;

  // -------- layer 2: K=256 (32 chunks) --------
  #pragma unroll 1
  for (int c = 0; c < 32; ++c){
    if (c < 31){
      s0 = *(const float4*)(w2t + (c+1)*2048 + tid*8);
      s1 = *(const float4*)(w2t + (c+1)*2048 + tid*8 + 4);
    }
    __syncthreads();
    gemm_chunk<8>(&wt[c&1][0], bufB, c*8, rg, pg, acc);
    if (c < 31){
      *(float4*)&wt[(c+1)&1][tid*8]     = s0;
      *(float4*)&wt[(c+1)&1][tid*8 + 4] = s1;
    }
  }

  // stage W3 into wt[0] (idle during chunk 31, which reads wt[1])
  {
    float4 w3r = *(const float4*)(w3t + tid*4);
    *(float4*)&wt[0][tid*4] = w3r;
  }
  // epilogue L2 -> bufA (h2); bufA idle since layer 1
  {
    const float4 bq = *(const float4*)(b2 + rg*4);
    const float ba[4] = {bq.x, bq.y, bq.z, bq.w};
    #pragma unroll
    for (int a = 0; a < 4; ++a){
      float4 v0, v1;
      v0.x = fmaxf(acc[a][0] + ba[a], 0.f); v0.y = fmaxf(acc[a][1] + ba[a], 0.f);
      v0.z = fmaxf(acc[a][2] + ba[a], 0.f); v0.w = fmaxf(acc[a][3] + ba[a], 0.f);
      v1.x = fmaxf(acc[a][4] + ba[a], 0.f); v1.y = fmaxf(acc[a][5] + ba[a], 0.f);
      v1.z = fmaxf(acc[a][6] + ba[a], 0.f); v1.w = fmaxf(acc[a][7] + ba[a], 0.f);
      *(float4*)&bufA[(rg*4 + a)*32 + pg*8]     = v0;
      *(float4*)&bufA[(rg*4 + a)*32 + pg*8 + 4] = v1;
    }
  }
  __syncthreads();

  // -------- layer 3: 3x256, 8 lanes per point + shuffle reduce --------
  const int p3 = tid >> 3, s3 = tid & 7;
  float a0 = 0.f, a1 = 0.f, a2 = 0.f;
  #pragma unroll 8
  for (int kk = 0; kk < 32; ++kk){
    int k = kk*8 + s3;
    float h = bufA[k*32 + p3];
    float4 w = *(const float4*)&wt[0][k*4];
    a0 = fmaf(h, w.x, a0);
    a1 = fmaf(h, w.y, a1);
    a2 = fmaf(h, w.z, a2);
  }
  a0 += __shfl_xor(a0, 1); a0 += __shfl_xor(a0, 2); a0 += __shfl_xor(a0, 4);
  a1 += __shfl_xor(a1, 1); a1 += __shfl_xor(a1, 2); a1 += __shfl_xor(a1, 4);
  a2 += __shfl_xor(a2, 1); a2 += __shfl_xor(a2, 2); a2 += __shfl_xor(a2, 4);

  if (s3 == 0){
    float ox = a0 + b3[0], oy = a1 + b3[1], oz = a2 + b3[2];
    float nrm = sqrtf(ox*ox + oy*oy + oz*oz);
    float rg_ = fmaxf(nrm - (float)0.10825317547305482, 0.f);   // sqrt(3)/16 rounded to f32
    int cell = mycell;
    float fx = ((float)(cell >> 8)        + 0.5f) * 0.0625f - 0.5f;
    float fy = ((float)((cell >> 4) & 15) + 0.5f) * 0.0625f - 0.5f;
    float fz = ((float)(cell & 15)        + 0.5f) * 0.0625f - 0.5f;
    int pidx = p0 + p3;
    out[b*49152 +           pidx] = ox + fx;
    out[b*49152 + 16384 +   pidx] = oy + fy;
    out[b*49152 + 32768 +   pidx] = oz + fz;
    out[786432  + b*16384 + pidx] = rg_;
  }
}

extern "C" void kernel_launch(void* const* d_in, const int* in_sizes, int n_in,
                              void* d_out, int out_size, void* d_ws, size_t ws_size,
                              hipStream_t stream){
  const float* x     = (const float*)d_in[0];
  const float* dens  = (const float*)d_in[1];
  const float* noise = (const float*)d_in[2];
  const float* W1    = (const float*)d_in[3];
  const float* b1    = (const float*)d_in[4];
  const float* W2    = (const float*)d_in[5];
  const float* b2    = (const float*)d_in[6];
  const float* W3    = (const float*)d_in[7];
  const float* b3    = (const float*)d_in[8];

  char* ws = (char*)d_ws;
  u64*   keys = (u64*)(ws + 0);
  int*   base = (int*)(ws + 524288);
  int*   nv   = (int*)(ws + 786432);
  int*   rem  = (int*)(ws + 1048576);
  int*   pc   = (int*)(ws + 1048832);
  float* w1t  = (float*)(ws + 2097408);
  float* w2t  = (float*)(ws + 2171136);
  float* w3t  = (float*)(ws + 2433280);
  float* out  = (float*)d_out;

  kT<<<dim3(256),    dim3(256), 0, stream>>>(W1, W2, W3, w1t, w2t, w3t);
  kA<<<dim3(16),     dim3(256), 0, stream>>>(dens, keys, base, rem);
  kB<<<dim3(16, 16), dim3(256), 0, stream>>>(keys, base, rem, nv);
  kC<<<dim3(16),     dim3(256), 0, stream>>>(nv, pc);
  kD<<<dim3(512, 16), dim3(256), 0, stream>>>(x, noise, w1t, w2t, w3t, b1, b2, b3, pc, out);
}

// Round 2
// 158.882 us; speedup vs baseline: 4.4768x; 4.4768x over previous
//
#include <hip/hip_runtime.h>

typedef unsigned long long u64;
typedef _Float16 f16x8 __attribute__((ext_vector_type(8)));
typedef float    f32x4 __attribute__((ext_vector_type(4)));

#define G_    4096
#define NPTS  16384

union H8 { _Float16 h[8]; uint4 u; };
union H4 { _Float16 h[4]; uint2 u; };

// ---------------- ws layout (bytes) ----------------
// keys  u64 [16][4096]   @ 0         (524288)
// base  i32 [16][4096]   @ 524288    (262144)
// nv    i32 [16][4096]   @ 786432    (262144)
// rem   i32 [16]         @ 1048576   (64)
// pc    i32 [16][16384]  @ 1048832   (1048576)
// w1f   f16 [16][3][64][8]  @ 2097472  (49152)   A-fragment order, K padded 66->96
// w2f   f16 [16][8][64][8]  @ 2146624  (131072)
// w3f   f16 [8][64][8]      @ 2277696  (8192)    rows 3..15 zero
// total 2285888

// ---- per-batch: S (correctly-rounded f32 sum), base, frac keys, rem ----
__global__ void kA(const float* __restrict__ dens, u64* __restrict__ keys,
                   int* __restrict__ base, int* __restrict__ rem){
  __shared__ double sred[256];
  __shared__ int    ired[256];
  __shared__ float  Sf;
  const int b = blockIdx.x, t = threadIdx.x;
  const float* d = dens + b*G_;
  double s = 0.0;
  for (int j = 0; j < 16; ++j) s += (double)d[t + 256*j];
  sred[t] = s; __syncthreads();
  for (int off = 128; off > 0; off >>= 1){
    if (t < off) sred[t] += sred[t + off];
    __syncthreads();
  }
  if (t == 0) Sf = (float)sred[0];
  __syncthreads();
  const float S = Sf;
  int bs = 0;
  for (int j = 0; j < 16; ++j){
    int i = t + 256*j;
    float p  = d[i] / S;
    float sc = p * 16384.0f;      // exact (x2^14)
    float fl = floorf(sc);
    float fr = sc - fl;           // exact
    int bi = (int)fl;
    keys[b*G_ + i] = ((u64)__float_as_uint(fr) << 12) | (u64)(4095 - i);
    base[b*G_ + i] = bi;
    bs += bi;
  }
  ired[t] = bs; __syncthreads();
  for (int off = 128; off > 0; off >>= 1){
    if (t < off) ired[t] += ired[t + off];
    __syncthreads();
  }
  if (t == 0) rem[b] = 16384 - ired[0];
}

// ---- rank by counting: n = base + (rank < rem) ----
__global__ void kB(const u64* __restrict__ keys, const int* __restrict__ base,
                   const int* __restrict__ rem, int* __restrict__ nv){
  __shared__ u64 kb[4096];
  const int b = blockIdx.y, slice = blockIdx.x, t = threadIdx.x;
  const u64* kk = keys + b*G_;
  for (int j = t; j < 4096; j += 256) kb[j] = kk[j];
  __syncthreads();
  const int i = slice*256 + t;
  const u64 K = kb[i];
  int cnt = 0;
  #pragma unroll 8
  for (int j = 0; j < 4096; ++j) cnt += (kb[j] > K) ? 1 : 0;
  nv[b*G_ + i] = base[b*G_ + i] + ((cnt < rem[b]) ? 1 : 0);
}

// ---- prefix sum + expand to per-point cell ids ----
__global__ void kC(const int* __restrict__ nv, int* __restrict__ pc){
  __shared__ int psum[256];
  const int b = blockIdx.x, t = threadIdx.x;
  const int* n = nv + b*G_;
  int loc[16]; int s = 0;
  #pragma unroll
  for (int j = 0; j < 16; ++j){ loc[j] = n[t*16 + j]; s += loc[j]; }
  psum[t] = s; __syncthreads();
  for (int off = 1; off < 256; off <<= 1){
    int v = (t >= off) ? psum[t - off] : 0;
    __syncthreads();
    psum[t] += v;
    __syncthreads();
  }
  int off0 = psum[t] - s;
  int* o = pc + b*NPTS;
  #pragma unroll
  for (int j = 0; j < 16; ++j){
    int c = t*16 + j;
    for (int r = 0; r < loc[j]; ++r) o[off0++] = c;
  }
}

// ---- bake weights into f16 A-fragment order ----
// A-frag layout assumption (16x16x32): lane l holds A[m = l&15][k = (l>>4)*8 + j], j=0..7.
// record for (row-tile RT, k-tile kt): 64 lanes x 8 halves, lane-linear 16B.
__global__ void kW(const float* __restrict__ W1, const float* __restrict__ W2,
                   const float* __restrict__ W3,
                   _Float16* __restrict__ w1f, _Float16* __restrict__ w2f,
                   _Float16* __restrict__ w3f){
  const int e = blockIdx.x*256 + threadIdx.x;   // 11776 entries total
  H8 v;
  if (e < 8192){                                 // w2f: [RT 16][kt 8][lane 64]
    const int RT = e >> 9, kt = (e >> 6) & 7, l = e & 63;
    const int m = RT*16 + (l & 15), k = kt*32 + ((l >> 4) << 3);
    #pragma unroll
    for (int j = 0; j < 8; ++j) v.h[j] = (_Float16)W2[m*256 + k + j];
    *(uint4*)&w2f[e*8] = v.u;
  } else if (e < 11264){                         // w1f: [RT 16][kt 3][lane 64]
    const int e2 = e - 8192;
    const int RT = e2 / 192, r2 = e2 % 192, kt = r2 >> 6, l = r2 & 63;
    const int m = RT*16 + (l & 15), k = kt*32 + ((l >> 4) << 3);
    #pragma unroll
    for (int j = 0; j < 8; ++j) v.h[j] = (k + j < 66) ? (_Float16)W1[m*66 + k + j] : (_Float16)0.f;
    *(uint4*)&w1f[e2*8] = v.u;
  } else if (e < 11776){                         // w3f: [kt 8][lane 64], rows>=3 zero
    const int e3 = e - 11264;
    const int kt = e3 >> 6, l = e3 & 63;
    const int m = l & 15, k = kt*32 + ((l >> 4) << 3);
    #pragma unroll
    for (int j = 0; j < 8; ++j) v.h[j] = (m < 3) ? (_Float16)W3[m*256 + k + j] : (_Float16)0.f;
    *(uint4*)&w3f[e3*8] = v.u;
  }
}

// ---- fused MLP via f16 MFMA: 64 points/block, 4 waves, wave = 64 rows x 64 pts ----
__global__ __launch_bounds__(256) void kE(
    const float* __restrict__ x, const float* __restrict__ noise,
    const _Float16* __restrict__ w1f, const _Float16* __restrict__ w2f,
    const _Float16* __restrict__ w3f,
    const float* __restrict__ b1, const float* __restrict__ b2, const float* __restrict__ b3,
    const int* __restrict__ pc, float* __restrict__ out)
{
  __shared__ _Float16 Hb[16384];   // 32KB; reused: Bin(12KB) -> Bh1(32KB) -> Bh2(32KB)
  __shared__ int cells[64];
  const int b = blockIdx.y, p0 = blockIdx.x*64, tid = threadIdx.x;
  const int w = tid >> 6, lane = tid & 63;

  if (tid < 64) cells[tid] = pc[b*NPTS + p0 + tid];
  __syncthreads();

  // ---- stage layer-1 input (fragment order): thread -> (koct=tid&3, pt=tid>>2) ----
  {
    const int koct = tid & 3, pt = tid >> 2;
    const int ct = pt >> 4, lane2 = (pt & 15) + koct*16;
    const int cell = cells[pt];
    #pragma unroll
    for (int kt = 0; kt < 3; ++kt){
      const int kbase = kt*32 + koct*8;
      H8 v;
      if (kbase < 64){
        const float* xb = x + ((size_t)(b*64 + kbase))*G_ + cell;
        #pragma unroll
        for (int j = 0; j < 8; ++j) v.h[j] = (_Float16)xb[(size_t)j*G_];
      } else if (kbase == 64){
        float n0 = noise[(b*2 + 0)*NPTS + p0 + pt]*2.f - 1.f;
        float n1 = noise[(b*2 + 1)*NPTS + p0 + pt]*2.f - 1.f;
        v.h[0] = (_Float16)n0; v.h[1] = (_Float16)n1;
        #pragma unroll
        for (int j = 2; j < 8; ++j) v.h[j] = (_Float16)0.f;
      } else {
        #pragma unroll
        for (int j = 0; j < 8; ++j) v.h[j] = (_Float16)0.f;
      }
      *(uint4*)&Hb[((kt*4 + ct)*64 + lane2)*8] = v.u;
    }
  }
  __syncthreads();

  f32x4 acc[4][4];
  const f32x4 zz = {0.f, 0.f, 0.f, 0.f};
  #pragma unroll
  for (int rt = 0; rt < 4; ++rt)
    #pragma unroll
    for (int ct = 0; ct < 4; ++ct) acc[rt][ct] = zz;

  const int wr = w*4;   // global row-tile base for this wave

  // -------- layer 1: K=96 (3 k-tiles) --------
  #pragma unroll
  for (int kt = 0; kt < 3; ++kt){
    f16x8 B[4];
    #pragma unroll
    for (int ct = 0; ct < 4; ++ct) B[ct] = *(f16x8*)&Hb[((kt*4 + ct)*64 + lane)*8];
    #pragma unroll
    for (int rt = 0; rt < 4; ++rt){
      f16x8 A = *(const f16x8*)&w1f[(((wr + rt)*3 + kt)*64 + lane)*8];
      #pragma unroll
      for (int ct = 0; ct < 4; ++ct)
        acc[rt][ct] = __builtin_amdgcn_mfma_f32_16x16x32_f16(A, B[ct], acc[rt][ct], 0, 0, 0);
    }
  }
  __syncthreads();

  // -------- epilogue L1: bias+relu -> f16 fragment order (Bh1) --------
  #pragma unroll
  for (int rt = 0; rt < 4; ++rt){
    const int row0 = w*64 + rt*16 + ((lane >> 4) << 2);
    const float bb0 = b1[row0], bb1 = b1[row0+1], bb2 = b1[row0+2], bb3 = b1[row0+3];
    const int kt2 = row0 >> 5, c16 = (row0 >> 3) & 3, j0 = row0 & 7;
    const int lane2 = (lane & 15) + c16*16;
    #pragma unroll
    for (int ct = 0; ct < 4; ++ct){
      H4 v;
      v.h[0] = (_Float16)fmaxf(acc[rt][ct][0] + bb0, 0.f);
      v.h[1] = (_Float16)fmaxf(acc[rt][ct][1] + bb1, 0.f);
      v.h[2] = (_Float16)fmaxf(acc[rt][ct][2] + bb2, 0.f);
      v.h[3] = (_Float16)fmaxf(acc[rt][ct][3] + bb3, 0.f);
      *(uint2*)&Hb[((kt2*4 + ct)*64 + lane2)*8 + j0] = v.u;
      acc[rt][ct] = zz;
    }
  }
  __syncthreads();

  // -------- layer 2: K=256 (8 k-tiles) --------
  #pragma unroll 2
  for (int kt = 0; kt < 8; ++kt){
    f16x8 B[4];
    #pragma unroll
    for (int ct = 0; ct < 4; ++ct) B[ct] = *(f16x8*)&Hb[((kt*4 + ct)*64 + lane)*8];
    #pragma unroll
    for (int rt = 0; rt < 4; ++rt){
      f16x8 A = *(const f16x8*)&w2f[(((wr + rt)*8 + kt)*64 + lane)*8];
      #pragma unroll
      for (int ct = 0; ct < 4; ++ct)
        acc[rt][ct] = __builtin_amdgcn_mfma_f32_16x16x32_f16(A, B[ct], acc[rt][ct], 0, 0, 0);
    }
  }
  __syncthreads();

  // -------- epilogue L2: bias+relu -> f16 fragment order (Bh2) --------
  #pragma unroll
  for (int rt = 0; rt < 4; ++rt){
    const int row0 = w*64 + rt*16 + ((lane >> 4) << 2);
    const float bb0 = b2[row0], bb1 = b2[row0+1], bb2 = b2[row0+2], bb3 = b2[row0+3];
    const int kt2 = row0 >> 5, c16 = (row0 >> 3) & 3, j0 = row0 & 7;
    const int lane2 = (lane & 15) + c16*16;
    #pragma unroll
    for (int ct = 0; ct < 4; ++ct){
      H4 v;
      v.h[0] = (_Float16)fmaxf(acc[rt][ct][0] + bb0, 0.f);
      v.h[1] = (_Float16)fmaxf(acc[rt][ct][1] + bb1, 0.f);
      v.h[2] = (_Float16)fmaxf(acc[rt][ct][2] + bb2, 0.f);
      v.h[3] = (_Float16)fmaxf(acc[rt][ct][3] + bb3, 0.f);
      *(uint2*)&Hb[((kt2*4 + ct)*64 + lane2)*8 + j0] = v.u;
    }
  }
  __syncthreads();

  // -------- layer 3: rows 0..2 (one row-tile), wave w handles col-tile w --------
  f32x4 a3 = zz;
  #pragma unroll
  for (int kt = 0; kt < 8; ++kt){
    f16x8 B = *(f16x8*)&Hb[((kt*4 + w)*64 + lane)*8];
    f16x8 A = *(const f16x8*)&w3f[(kt*64 + lane)*8];
    a3 = __builtin_amdgcn_mfma_f32_16x16x32_f16(A, B, a3, 0, 0, 0);
  }
  if (lane < 16){
    const float ox = a3[0] + b3[0];
    const float oy = a3[1] + b3[1];
    const float oz = a3[2] + b3[2];
    const float nrm = sqrtf(ox*ox + oy*oy + oz*oz);
    const float rg_ = fmaxf(nrm - (float)0.10825317547305482, 0.f);
    const int pt = w*16 + lane;
    const int cell = cells[pt];
    const float fx = ((float)(cell >> 8)        + 0.5f) * 0.0625f - 0.5f;
    const float fy = ((float)((cell >> 4) & 15) + 0.5f) * 0.0625f - 0.5f;
    const float fz = ((float)(cell & 15)        + 0.5f) * 0.0625f - 0.5f;
    const int pidx = p0 + pt;
    out[b*49152 +          pidx] = ox + fx;
    out[b*49152 + 16384 +  pidx] = oy + fy;
    out[b*49152 + 32768 +  pidx] = oz + fz;
    out[786432  + b*16384 + pidx] = rg_;
  }
}

extern "C" void kernel_launch(void* const* d_in, const int* in_sizes, int n_in,
                              void* d_out, int out_size, void* d_ws, size_t ws_size,
                              hipStream_t stream){
  const float* x     = (const float*)d_in[0];
  const float* dens  = (const float*)d_in[1];
  const float* noise = (const float*)d_in[2];
  const float* W1    = (const float*)d_in[3];
  const float* b1    = (const float*)d_in[4];
  const float* W2    = (const float*)d_in[5];
  const float* b2    = (const float*)d_in[6];
  const float* W3    = (const float*)d_in[7];
  const float* b3    = (const float*)d_in[8];

  char* ws = (char*)d_ws;
  u64*      keys = (u64*)(ws + 0);
  int*      base = (int*)(ws + 524288);
  int*      nv   = (int*)(ws + 786432);
  int*      rem  = (int*)(ws + 1048576);
  int*      pc   = (int*)(ws + 1048832);
  _Float16* w1f  = (_Float16*)(ws + 2097472);
  _Float16* w2f  = (_Float16*)(ws + 2146624);
  _Float16* w3f  = (_Float16*)(ws + 2277696);
  float*    out  = (float*)d_out;

  kW<<<dim3(46),      dim3(256), 0, stream>>>(W1, W2, W3, w1f, w2f, w3f);
  kA<<<dim3(16),      dim3(256), 0, stream>>>(dens, keys, base, rem);
  kB<<<dim3(16, 16),  dim3(256), 0, stream>>>(keys, base, rem, nv);
  kC<<<dim3(16),      dim3(256), 0, stream>>>(nv, pc);
  kE<<<dim3(256, 16), dim3(256), 0, stream>>>(x, noise, w1f, w2f, w3f, b1, b2, b3, pc, out);
}

// Round 3
// 111.698 us; speedup vs baseline: 6.3679x; 1.4224x over previous
//
#include <hip/hip_runtime.h>

typedef unsigned long long u64;
typedef _Float16 f16x8 __attribute__((ext_vector_type(8)));
typedef float    f32x4 __attribute__((ext_vector_type(4)));

#define G_    4096
#define NPTS  16384

union H8 { _Float16 h[8]; uint4 u; };
union H4 { _Float16 h[4]; uint2 u; };

// ---------------- ws layout (bytes) ----------------
// pc   i32 [16][16384]    @ 0        (1048576)
// w1f  f16 [16][2][64][8] @ 1048576  (32768)   A-frag order, K=64 (x channels only)
// w2f  f16 [16][8][64][8] @ 1081344  (131072)
// w3f  f16 [8][64][8]     @ 1212416  (8192)    rows 3..15 zero
// w1n  f32 [256][2]       @ 1220608  (2048)    W1 cols 64,65 (noise channels)
// total 1222656

// ---- bake weights into f16 A-fragment order ----
// A-frag (16x16x32): lane l holds A[m = l&15][k = (l>>4)*8 + j], j=0..7.
__global__ void kW(const float* __restrict__ W1, const float* __restrict__ W2,
                   const float* __restrict__ W3,
                   _Float16* __restrict__ w1f, _Float16* __restrict__ w2f,
                   _Float16* __restrict__ w3f, float* __restrict__ w1n){
  const int e = blockIdx.x*256 + threadIdx.x;   // 11008 entries
  H8 v;
  if (e < 8192){                                 // w2f: [RT 16][kt 8][lane 64]
    const int RT = e >> 9, kt = (e >> 6) & 7, l = e & 63;
    const int m = RT*16 + (l & 15), k = kt*32 + ((l >> 4) << 3);
    #pragma unroll
    for (int j = 0; j < 8; ++j) v.h[j] = (_Float16)W2[m*256 + k + j];
    *(uint4*)&w2f[e*8] = v.u;
  } else if (e < 10240){                         // w1f: [RT 16][kt 2][lane 64]
    const int e2 = e - 8192;
    const int RT = e2 >> 7, r2 = e2 & 127, kt = r2 >> 6, l = r2 & 63;
    const int m = RT*16 + (l & 15), k = kt*32 + ((l >> 4) << 3);   // k < 64
    #pragma unroll
    for (int j = 0; j < 8; ++j) v.h[j] = (_Float16)W1[m*66 + k + j];
    *(uint4*)&w1f[e2*8] = v.u;
  } else if (e < 10752){                         // w3f: [kt 8][lane 64]
    const int e3 = e - 10240;
    const int kt = e3 >> 6, l = e3 & 63;
    const int m = l & 15, k = kt*32 + ((l >> 4) << 3);
    #pragma unroll
    for (int j = 0; j < 8; ++j) v.h[j] = (m < 3) ? (_Float16)W3[m*256 + k + j] : (_Float16)0.f;
    *(uint4*)&w3f[e3*8] = v.u;
  } else if (e < 11008){                         // w1n: noise-channel cols
    const int r = e - 10752;
    w1n[r*2 + 0] = W1[r*66 + 64];
    w1n[r*2 + 1] = W1[r*66 + 65];
  }
}

// ---- fused sampling: sum -> keys -> histogram-select threshold -> counts -> expand ----
__global__ __launch_bounds__(256) void kS(const float* __restrict__ dens,
                                          int* __restrict__ pc){
  __shared__ double sred[256];
  __shared__ u64  keys[4096];     // 32 KB
  __shared__ int  nvs[4096];      // 16 KB
  __shared__ int  binidx[4096];   // 16 KB
  __shared__ int  hist[1024];
  __shared__ int  cab[1024];
  __shared__ int  scan[256];
  __shared__ float Sf;
  __shared__ int  remS, BstarS, needS, cntS;
  const int b = blockIdx.x, t = threadIdx.x;
  const float* d = dens + b*G_;

  for (int j = t; j < 1024; j += 256) hist[j] = 0;
  if (t == 0) cntS = 0;

  // exact same summation pattern as passing rounds: per-thread d[t+256j], tree over 256
  double s = 0.0;
  for (int j = 0; j < 16; ++j) s += (double)d[t + 256*j];
  sred[t] = s; __syncthreads();
  for (int off = 128; off > 0; off >>= 1){
    if (t < off) sred[t] += sred[t + off];
    __syncthreads();
  }
  if (t == 0) Sf = (float)sred[0];
  __syncthreads();
  const float S = Sf;

  int bi[16]; int bs = 0;
  #pragma unroll
  for (int j = 0; j < 16; ++j){
    const int i = t + 256*j;
    const float p  = d[i] / S;
    const float sc = p * 16384.0f;     // exact (x2^14)
    const float fl = floorf(sc);
    const float fr = sc - fl;          // exact
    bi[j] = (int)fl; bs += bi[j];
    const unsigned fb = __float_as_uint(fr);
    keys[i] = ((u64)fb << 12) | (u64)(4095 - i);
    atomicAdd(&hist[fb >> 20], 1);
  }
  scan[t] = bs; __syncthreads();
  for (int off = 128; off > 0; off >>= 1){
    if (t < off) scan[t] += scan[t + off];
    __syncthreads();
  }
  if (t == 0) remS = 16384 - scan[0];
  __syncthreads();
  const int rem = remS;

  // suffix-scan histogram (1024 bins, 4/thread) -> cab[b] = #keys in bins > b
  const int h0 = hist[4*t], h1 = hist[4*t+1], h2 = hist[4*t+2], h3 = hist[4*t+3];
  const int gs = h0 + h1 + h2 + h3;
  __syncthreads();
  scan[t] = gs; __syncthreads();
  for (int off = 1; off < 256; off <<= 1){
    const int v2 = (t + off < 256) ? scan[t + off] : 0;
    __syncthreads();
    scan[t] += v2;
    __syncthreads();
  }
  const int sAfter = scan[t] - gs;
  cab[4*t+3] = sAfter;
  cab[4*t+2] = sAfter + h3;
  cab[4*t+1] = sAfter + h3 + h2;
  cab[4*t+0] = sAfter + h3 + h2 + h1;
  if (t == 0){ BstarS = 0x7fffffff; needS = 0; }
  __syncthreads();
  if (rem > 0){
    const int ca[4] = {cab[4*t], cab[4*t+1], cab[4*t+2], cab[4*t+3]};
    const int hh[4] = {h0, h1, h2, h3};
    #pragma unroll
    for (int q = 0; q < 4; ++q)
      if (ca[q] < rem && rem <= ca[q] + hh[q]){ BstarS = 4*t + q; needS = rem - ca[q]; }
  }
  __syncthreads();
  const int Bstar = BstarS, need = needS;

  #pragma unroll
  for (int j = 0; j < 16; ++j){
    const int i = t + 256*j;
    const int bin = (int)(keys[i] >> 32);
    nvs[i] = bi[j] + ((bin > Bstar) ? 1 : 0);
    if (bin == Bstar){ const int pos = atomicAdd(&cntS, 1); binidx[pos] = i; }
  }
  __syncthreads();
  const int cnt = cntS;
  for (int p = t; p < cnt; p += 256){
    const u64 K = keys[binidx[p]];
    int r = 0;
    for (int q = 0; q < cnt; ++q) r += (keys[binidx[q]] > K) ? 1 : 0;
    if (r < need) nvs[binidx[p]] += 1;
  }
  __syncthreads();

  // prefix + expand (thread t owns cells t*16..t*16+15)
  int loc[16]; int ls = 0;
  #pragma unroll
  for (int j = 0; j < 16; ++j){ loc[j] = nvs[t*16 + j]; ls += loc[j]; }
  __syncthreads();
  scan[t] = ls; __syncthreads();
  for (int off = 1; off < 256; off <<= 1){
    const int v2 = (t >= off) ? scan[t - off] : 0;
    __syncthreads();
    scan[t] += v2;
    __syncthreads();
  }
  int off0 = scan[t] - ls;
  int* o = pc + b*NPTS;
  #pragma unroll
  for (int j = 0; j < 16; ++j){
    const int c = t*16 + j;
    for (int r = 0; r < loc[j]; ++r) o[off0++] = c;
  }
}

// ---- fused MLP via f16 MFMA: 64 points/block, 4 waves, wave = 64 rows x 64 pts ----
__global__ __launch_bounds__(256, 4) void kE(
    const float* __restrict__ x, const float* __restrict__ noise,
    const _Float16* __restrict__ w1f, const _Float16* __restrict__ w2f,
    const _Float16* __restrict__ w3f, const float* __restrict__ w1n,
    const float* __restrict__ b1, const float* __restrict__ b2, const float* __restrict__ b3,
    const int* __restrict__ pc, float* __restrict__ out)
{
  __shared__ _Float16 Hb[16384];   // 32KB; reused: Bin(8KB) -> Bh1(32KB) -> Bh2(32KB)
  __shared__ int   cells[64];
  __shared__ float rndS[2][64];
  const int b = blockIdx.y, p0 = blockIdx.x*64, tid = threadIdx.x;
  const int w = tid >> 6, lane = tid & 63;

  if (tid < 64) cells[tid] = pc[b*NPTS + p0 + tid];
  if (tid >= 64 && tid < 192){
    const int rr = (tid - 64) >> 6, p = tid & 63;
    rndS[rr][p] = noise[(b*2 + rr)*NPTS + p0 + p]*2.f - 1.f;
  }
  __syncthreads();

  // ---- stage layer-1 input (fragment order): thread -> (koct=tid&3, pt=tid>>2) ----
  {
    const int koct = tid & 3, pt = tid >> 2;
    const int ct = pt >> 4, lane2 = (pt & 15) + koct*16;
    const int cell = cells[pt];
    #pragma unroll
    for (int kt = 0; kt < 2; ++kt){
      const int kbase = kt*32 + koct*8;            // < 64 always
      const float* xb = x + ((size_t)(b*64 + kbase))*G_ + cell;
      H8 v;
      #pragma unroll
      for (int j = 0; j < 8; ++j) v.h[j] = (_Float16)xb[(size_t)j*G_];
      *(uint4*)&Hb[((kt*4 + ct)*64 + lane2)*8] = v.u;
    }
  }
  __syncthreads();

  f32x4 acc[4][4];
  const f32x4 zz = {0.f, 0.f, 0.f, 0.f};
  #pragma unroll
  for (int rt = 0; rt < 4; ++rt)
    #pragma unroll
    for (int ct = 0; ct < 4; ++ct) acc[rt][ct] = zz;

  const int wr = w*4;

  // -------- layer 1: K=64 (2 k-tiles, x channels only) --------
  __builtin_amdgcn_s_setprio(1);
  #pragma unroll
  for (int kt = 0; kt < 2; ++kt){
    f16x8 B[4];
    #pragma unroll
    for (int ct = 0; ct < 4; ++ct) B[ct] = *(f16x8*)&Hb[((kt*4 + ct)*64 + lane)*8];
    #pragma unroll
    for (int rt = 0; rt < 4; ++rt){
      f16x8 A = *(const f16x8*)&w1f[(((wr + rt)*2 + kt)*64 + lane)*8];
      #pragma unroll
      for (int ct = 0; ct < 4; ++ct)
        acc[rt][ct] = __builtin_amdgcn_mfma_f32_16x16x32_f16(A, B[ct], acc[rt][ct], 0, 0, 0);
    }
  }
  __builtin_amdgcn_s_setprio(0);

  // ---- rank-2 noise update (f32): acc += w1[:,64] x rnd0 + w1[:,65] x rnd1 ----
  {
    const int m16 = lane & 15, khi = lane >> 4;
    float rn0[4], rn1[4];
    #pragma unroll
    for (int ct = 0; ct < 4; ++ct){
      rn0[ct] = rndS[0][ct*16 + m16];
      rn1[ct] = rndS[1][ct*16 + m16];
    }
    #pragma unroll
    for (int rt = 0; rt < 4; ++rt){
      const int row0 = w*64 + rt*16 + khi*4;
      const float4 wa = *(const float4*)&w1n[row0*2];       // rows row0,row0+1
      const float4 wb = *(const float4*)&w1n[row0*2 + 4];   // rows row0+2,row0+3
      #pragma unroll
      for (int ct = 0; ct < 4; ++ct){
        acc[rt][ct][0] += wa.x*rn0[ct] + wa.y*rn1[ct];
        acc[rt][ct][1] += wa.z*rn0[ct] + wa.w*rn1[ct];
        acc[rt][ct][2] += wb.x*rn0[ct] + wb.y*rn1[ct];
        acc[rt][ct][3] += wb.z*rn0[ct] + wb.w*rn1[ct];
      }
    }
  }
  __syncthreads();

  // -------- epilogue L1: bias+relu -> f16 fragment order (Bh1) --------
  #pragma unroll
  for (int rt = 0; rt < 4; ++rt){
    const int row0 = w*64 + rt*16 + ((lane >> 4) << 2);
    const float4 bq = *(const float4*)&b1[row0];
    const int kt2 = row0 >> 5, c16 = (row0 >> 3) & 3, j0 = row0 & 7;
    const int lane2 = (lane & 15) + c16*16;
    #pragma unroll
    for (int ct = 0; ct < 4; ++ct){
      H4 v;
      v.h[0] = (_Float16)fmaxf(acc[rt][ct][0] + bq.x, 0.f);
      v.h[1] = (_Float16)fmaxf(acc[rt][ct][1] + bq.y, 0.f);
      v.h[2] = (_Float16)fmaxf(acc[rt][ct][2] + bq.z, 0.f);
      v.h[3] = (_Float16)fmaxf(acc[rt][ct][3] + bq.w, 0.f);
      *(uint2*)&Hb[((kt2*4 + ct)*64 + lane2)*8 + j0] = v.u;
      acc[rt][ct] = zz;
    }
  }
  __syncthreads();

  // -------- layer 2: K=256 (8 k-tiles) --------
  __builtin_amdgcn_s_setprio(1);
  #pragma unroll 4
  for (int kt = 0; kt < 8; ++kt){
    f16x8 B[4];
    #pragma unroll
    for (int ct = 0; ct < 4; ++ct) B[ct] = *(f16x8*)&Hb[((kt*4 + ct)*64 + lane)*8];
    #pragma unroll
    for (int rt = 0; rt < 4; ++rt){
      f16x8 A = *(const f16x8*)&w2f[(((wr + rt)*8 + kt)*64 + lane)*8];
      #pragma unroll
      for (int ct = 0; ct < 4; ++ct)
        acc[rt][ct] = __builtin_amdgcn_mfma_f32_16x16x32_f16(A, B[ct], acc[rt][ct], 0, 0, 0);
    }
  }
  __builtin_amdgcn_s_setprio(0);
  __syncthreads();

  // -------- epilogue L2: bias+relu -> f16 fragment order (Bh2) --------
  #pragma unroll
  for (int rt = 0; rt < 4; ++rt){
    const int row0 = w*64 + rt*16 + ((lane >> 4) << 2);
    const float4 bq = *(const float4*)&b2[row0];
    const int kt2 = row0 >> 5, c16 = (row0 >> 3) & 3, j0 = row0 & 7;
    const int lane2 = (lane & 15) + c16*16;
    #pragma unroll
    for (int ct = 0; ct < 4; ++ct){
      H4 v;
      v.h[0] = (_Float16)fmaxf(acc[rt][ct][0] + bq.x, 0.f);
      v.h[1] = (_Float16)fmaxf(acc[rt][ct][1] + bq.y, 0.f);
      v.h[2] = (_Float16)fmaxf(acc[rt][ct][2] + bq.z, 0.f);
      v.h[3] = (_Float16)fmaxf(acc[rt][ct][3] + bq.w, 0.f);
      *(uint2*)&Hb[((kt2*4 + ct)*64 + lane2)*8 + j0] = v.u;
    }
  }
  __syncthreads();

  // -------- layer 3: rows 0..2, wave w handles col-tile w --------
  f32x4 a3 = zz;
  #pragma unroll
  for (int kt = 0; kt < 8; ++kt){
    f16x8 B = *(f16x8*)&Hb[((kt*4 + w)*64 + lane)*8];
    f16x8 A = *(const f16x8*)&w3f[(kt*64 + lane)*8];
    a3 = __builtin_amdgcn_mfma_f32_16x16x32_f16(A, B, a3, 0, 0, 0);
  }
  if (lane < 16){
    const float ox = a3[0] + b3[0];
    const float oy = a3[1] + b3[1];
    const float oz = a3[2] + b3[2];
    const float nrm = sqrtf(ox*ox + oy*oy + oz*oz);
    const float rg_ = fmaxf(nrm - (float)0.10825317547305482, 0.f);
    const int pt = w*16 + lane;
    const int cell = cells[pt];
    const float fx = ((float)(cell >> 8)        + 0.5f) * 0.0625f - 0.5f;
    const float fy = ((float)((cell >> 4) & 15) + 0.5f) * 0.0625f - 0.5f;
    const float fz = ((float)(cell & 15)        + 0.5f) * 0.0625f - 0.5f;
    const int pidx = p0 + pt;
    out[b*49152 +          pidx] = ox + fx;
    out[b*49152 + 16384 +  pidx] = oy + fy;
    out[b*49152 + 32768 +  pidx] = oz + fz;
    out[786432  + b*16384 + pidx] = rg_;
  }
}

extern "C" void kernel_launch(void* const* d_in, const int* in_sizes, int n_in,
                              void* d_out, int out_size, void* d_ws, size_t ws_size,
                              hipStream_t stream){
  const float* x     = (const float*)d_in[0];
  const float* dens  = (const float*)d_in[1];
  const float* noise = (const float*)d_in[2];
  const float* W1    = (const float*)d_in[3];
  const float* b1    = (const float*)d_in[4];
  const float* W2    = (const float*)d_in[5];
  const float* b2    = (const float*)d_in[6];
  const float* W3    = (const float*)d_in[7];
  const float* b3    = (const float*)d_in[8];

  char* ws = (char*)d_ws;
  int*      pc   = (int*)(ws + 0);
  _Float16* w1f  = (_Float16*)(ws + 1048576);
  _Float16* w2f  = (_Float16*)(ws + 1081344);
  _Float16* w3f  = (_Float16*)(ws + 1212416);
  float*    w1n  = (float*)(ws + 1220608);
  float*    out  = (float*)d_out;

  kW<<<dim3(43),      dim3(256), 0, stream>>>(W1, W2, W3, w1f, w2f, w3f, w1n);
  kS<<<dim3(16),      dim3(256), 0, stream>>>(dens, pc);
  kE<<<dim3(256, 16), dim3(256), 0, stream>>>(x, noise, w1f, w2f, w3f, w1n,
                                              b1, b2, b3, pc, out);
}

// Round 4
// 86.261 us; speedup vs baseline: 8.2457x; 1.2949x over previous
//
#include <hip/hip_runtime.h>

typedef unsigned long long u64;
typedef _Float16 f16x8 __attribute__((ext_vector_type(8)));
typedef float    f32x4 __attribute__((ext_vector_type(4)));

#define G_    4096
#define NPTS  16384

union H8 { _Float16 h[8]; uint4 u; };
union H4 { _Float16 h[4]; uint2 u; };

// ---------------- ws layout (bytes) ----------------
// pc   i32 [16][16384]    @ 0        (1048576)
// w1f  f16 [16][2][64][8] @ 1048576  (32768)   A-frag order, K=64 (x channels only)
// w2f  f16 [16][8][64][8] @ 1081344  (131072)
// w3f  f16 [8][64][8]     @ 1212416  (8192)    rows 3..15 zero
// w1n  f32 [256][2]       @ 1220608  (2048)    W1 cols 64,65 (noise channels)
// total 1222656

// ---- merged prep: blocks 0..15 = sampling (per batch); blocks 16..58 = weight bake ----
__global__ __launch_bounds__(256) void kP(const float* __restrict__ dens,
                                          int* __restrict__ pc,
                                          const float* __restrict__ W1,
                                          const float* __restrict__ W2,
                                          const float* __restrict__ W3,
                                          _Float16* __restrict__ w1f,
                                          _Float16* __restrict__ w2f,
                                          _Float16* __restrict__ w3f,
                                          float* __restrict__ w1n){
  __shared__ double sred[256];
  __shared__ u64  keys[4096];     // 32 KB
  __shared__ int  nvs[4096];      // 16 KB
  __shared__ int  binidx[4096];   // 16 KB
  __shared__ int  hist[1024];
  __shared__ int  cab[1024];
  __shared__ int  scan[256];
  __shared__ float Sf;
  __shared__ int  remS, BstarS, needS, cntS;
  const int t = threadIdx.x;

  if (blockIdx.x >= 16){
    // ---------------- weight bake path ----------------
    const int e = (blockIdx.x - 16)*256 + t;   // 11008 entries
    H8 v;
    if (e < 8192){                                 // w2f: [RT 16][kt 8][lane 64]
      const int RT = e >> 9, kt = (e >> 6) & 7, l = e & 63;
      const int m = RT*16 + (l & 15), k = kt*32 + ((l >> 4) << 3);
      #pragma unroll
      for (int j = 0; j < 8; ++j) v.h[j] = (_Float16)W2[m*256 + k + j];
      *(uint4*)&w2f[e*8] = v.u;
    } else if (e < 10240){                         // w1f: [RT 16][kt 2][lane 64]
      const int e2 = e - 8192;
      const int RT = e2 >> 7, r2 = e2 & 127, kt = r2 >> 6, l = r2 & 63;
      const int m = RT*16 + (l & 15), k = kt*32 + ((l >> 4) << 3);   // k < 64
      #pragma unroll
      for (int j = 0; j < 8; ++j) v.h[j] = (_Float16)W1[m*66 + k + j];
      *(uint4*)&w1f[e2*8] = v.u;
    } else if (e < 10752){                         // w3f: [kt 8][lane 64]
      const int e3 = e - 10240;
      const int kt = e3 >> 6, l = e3 & 63;
      const int m = l & 15, k = kt*32 + ((l >> 4) << 3);
      #pragma unroll
      for (int j = 0; j < 8; ++j) v.h[j] = (m < 3) ? (_Float16)W3[m*256 + k + j] : (_Float16)0.f;
      *(uint4*)&w3f[e3*8] = v.u;
    } else if (e < 11008){                         // w1n: noise-channel cols
      const int r = e - 10752;
      w1n[r*2 + 0] = W1[r*66 + 64];
      w1n[r*2 + 1] = W1[r*66 + 65];
    }
    return;
  }

  // ---------------- sampling path (one block per batch) ----------------
  const int b = blockIdx.x;
  const float* d = dens + b*G_;

  for (int j = t; j < 1024; j += 256) hist[j] = 0;
  if (t == 0) cntS = 0;

  // exact same summation pattern as passing rounds: per-thread d[t+256j], tree over 256
  double s = 0.0;
  for (int j = 0; j < 16; ++j) s += (double)d[t + 256*j];
  sred[t] = s; __syncthreads();
  for (int off = 128; off > 0; off >>= 1){
    if (t < off) sred[t] += sred[t + off];
    __syncthreads();
  }
  if (t == 0) Sf = (float)sred[0];
  __syncthreads();
  const float S = Sf;

  int bi[16]; int bs = 0;
  #pragma unroll
  for (int j = 0; j < 16; ++j){
    const int i = t + 256*j;
    const float p  = d[i] / S;
    const float sc = p * 16384.0f;     // exact (x2^14)
    const float fl = floorf(sc);
    const float fr = sc - fl;          // exact
    bi[j] = (int)fl; bs += bi[j];
    const unsigned fb = __float_as_uint(fr);
    keys[i] = ((u64)fb << 12) | (u64)(4095 - i);
    atomicAdd(&hist[fb >> 20], 1);
  }
  scan[t] = bs; __syncthreads();
  for (int off = 128; off > 0; off >>= 1){
    if (t < off) scan[t] += scan[t + off];
    __syncthreads();
  }
  if (t == 0) remS = 16384 - scan[0];
  __syncthreads();
  const int rem = remS;

  // suffix-scan histogram (1024 bins, 4/thread) -> cab[q] = #keys in bins > q
  const int h0 = hist[4*t], h1 = hist[4*t+1], h2 = hist[4*t+2], h3 = hist[4*t+3];
  const int gs = h0 + h1 + h2 + h3;
  __syncthreads();
  scan[t] = gs; __syncthreads();
  for (int off = 1; off < 256; off <<= 1){
    const int v2 = (t + off < 256) ? scan[t + off] : 0;
    __syncthreads();
    scan[t] += v2;
    __syncthreads();
  }
  const int sAfter = scan[t] - gs;
  cab[4*t+3] = sAfter;
  cab[4*t+2] = sAfter + h3;
  cab[4*t+1] = sAfter + h3 + h2;
  cab[4*t+0] = sAfter + h3 + h2 + h1;
  if (t == 0){ BstarS = 0x7fffffff; needS = 0; }
  __syncthreads();
  if (rem > 0){
    const int ca[4] = {cab[4*t], cab[4*t+1], cab[4*t+2], cab[4*t+3]};
    const int hh[4] = {h0, h1, h2, h3};
    #pragma unroll
    for (int q = 0; q < 4; ++q)
      if (ca[q] < rem && rem <= ca[q] + hh[q]){ BstarS = 4*t + q; needS = rem - ca[q]; }
  }
  __syncthreads();
  const int Bstar = BstarS, need = needS;

  #pragma unroll
  for (int j = 0; j < 16; ++j){
    const int i = t + 256*j;
    const int bin = (int)(keys[i] >> 32);
    nvs[i] = bi[j] + ((bin > Bstar) ? 1 : 0);
    if (bin == Bstar){ const int pos = atomicAdd(&cntS, 1); binidx[pos] = i; }
  }
  __syncthreads();
  const int cnt = cntS;
  for (int p = t; p < cnt; p += 256){
    const u64 K = keys[binidx[p]];
    int r = 0;
    for (int q = 0; q < cnt; ++q) r += (keys[binidx[q]] > K) ? 1 : 0;
    if (r < need) nvs[binidx[p]] += 1;
  }
  __syncthreads();

  // prefix + expand (thread t owns cells t*16..t*16+15)
  int loc[16]; int ls = 0;
  #pragma unroll
  for (int j = 0; j < 16; ++j){ loc[j] = nvs[t*16 + j]; ls += loc[j]; }
  __syncthreads();
  scan[t] = ls; __syncthreads();
  for (int off = 1; off < 256; off <<= 1){
    const int v2 = (t >= off) ? scan[t - off] : 0;
    __syncthreads();
    scan[t] += v2;
    __syncthreads();
  }
  int off0 = scan[t] - ls;
  int* o = pc + b*NPTS;
  #pragma unroll
  for (int j = 0; j < 16; ++j){
    const int c = t*16 + j;
    for (int r = 0; r < loc[j]; ++r) o[off0++] = c;
  }
}

// ---- fused MLP via f16 MFMA: 64 points/block, 4 waves, wave = 64 rows x 64 pts ----
// reg budget: 64 acc (AGPR side) + ~100 arch = 164 <= 512/3 -> 3 blocks/CU, no spill.
__global__ __launch_bounds__(256, 3) void kE(
    const float* __restrict__ x, const float* __restrict__ noise,
    const _Float16* __restrict__ w1f, const _Float16* __restrict__ w2f,
    const _Float16* __restrict__ w3f, const float* __restrict__ w1n,
    const float* __restrict__ b1, const float* __restrict__ b2, const float* __restrict__ b3,
    const int* __restrict__ pc, float* __restrict__ out)
{
  __shared__ _Float16 Hb[16384];   // 32KB; reused: Bin(8KB) -> Bh1(32KB) -> Bh2(32KB)
  __shared__ int   cells[64];
  __shared__ float rndS[2][64];
  const int b = blockIdx.y, p0 = blockIdx.x*64, tid = threadIdx.x;
  const int w = tid >> 6, lane = tid & 63;

  if (tid < 64) cells[tid] = pc[b*NPTS + p0 + tid];
  if (tid >= 64 && tid < 192){
    const int rr = (tid - 64) >> 6, p = tid & 63;
    rndS[rr][p] = noise[(b*2 + rr)*NPTS + p0 + p]*2.f - 1.f;
  }
  __syncthreads();

  // ---- stage layer-1 input (fragment order): thread -> (koct=tid&3, pt=tid>>2) ----
  {
    const int koct = tid & 3, pt = tid >> 2;
    const int ct = pt >> 4, lane2 = (pt & 15) + koct*16;
    const int cell = cells[pt];
    #pragma unroll
    for (int kt = 0; kt < 2; ++kt){
      const int kbase = kt*32 + koct*8;            // < 64 always
      const float* xb = x + ((size_t)(b*64 + kbase))*G_ + cell;
      H8 v;
      #pragma unroll
      for (int j = 0; j < 8; ++j) v.h[j] = (_Float16)xb[(size_t)j*G_];
      *(uint4*)&Hb[((kt*4 + ct)*64 + lane2)*8] = v.u;
    }
  }
  __syncthreads();

  f32x4 acc[4][4];
  const f32x4 zz = {0.f, 0.f, 0.f, 0.f};
  #pragma unroll
  for (int rt = 0; rt < 4; ++rt)
    #pragma unroll
    for (int ct = 0; ct < 4; ++ct) acc[rt][ct] = zz;

  const int wr = w*4;

  // -------- layer 1: K=64 (2 k-tiles, x channels only) --------
  __builtin_amdgcn_s_setprio(1);
  #pragma unroll
  for (int kt = 0; kt < 2; ++kt){
    f16x8 B[4];
    #pragma unroll
    for (int ct = 0; ct < 4; ++ct) B[ct] = *(f16x8*)&Hb[((kt*4 + ct)*64 + lane)*8];
    #pragma unroll
    for (int rt = 0; rt < 4; ++rt){
      f16x8 A = *(const f16x8*)&w1f[(((wr + rt)*2 + kt)*64 + lane)*8];
      #pragma unroll
      for (int ct = 0; ct < 4; ++ct)
        acc[rt][ct] = __builtin_amdgcn_mfma_f32_16x16x32_f16(A, B[ct], acc[rt][ct], 0, 0, 0);
    }
  }
  __builtin_amdgcn_s_setprio(0);

  // ---- rank-2 noise update (f32): acc += w1[:,64] x rnd0 + w1[:,65] x rnd1 ----
  {
    const int m16 = lane & 15, khi = lane >> 4;
    float rn0[4], rn1[4];
    #pragma unroll
    for (int ct = 0; ct < 4; ++ct){
      rn0[ct] = rndS[0][ct*16 + m16];
      rn1[ct] = rndS[1][ct*16 + m16];
    }
    #pragma unroll
    for (int rt = 0; rt < 4; ++rt){
      const int row0 = w*64 + rt*16 + khi*4;
      const float4 wa = *(const float4*)&w1n[row0*2];       // rows row0,row0+1
      const float4 wb = *(const float4*)&w1n[row0*2 + 4];   // rows row0+2,row0+3
      #pragma unroll
      for (int ct = 0; ct < 4; ++ct){
        acc[rt][ct][0] += wa.x*rn0[ct] + wa.y*rn1[ct];
        acc[rt][ct][1] += wa.z*rn0[ct] + wa.w*rn1[ct];
        acc[rt][ct][2] += wb.x*rn0[ct] + wb.y*rn1[ct];
        acc[rt][ct][3] += wb.z*rn0[ct] + wb.w*rn1[ct];
      }
    }
  }
  __syncthreads();

  // -------- epilogue L1: bias+relu -> f16 fragment order (Bh1) --------
  #pragma unroll
  for (int rt = 0; rt < 4; ++rt){
    const int row0 = w*64 + rt*16 + ((lane >> 4) << 2);
    const float4 bq = *(const float4*)&b1[row0];
    const int kt2 = row0 >> 5, c16 = (row0 >> 3) & 3, j0 = row0 & 7;
    const int lane2 = (lane & 15) + c16*16;
    #pragma unroll
    for (int ct = 0; ct < 4; ++ct){
      H4 v;
      v.h[0] = (_Float16)fmaxf(acc[rt][ct][0] + bq.x, 0.f);
      v.h[1] = (_Float16)fmaxf(acc[rt][ct][1] + bq.y, 0.f);
      v.h[2] = (_Float16)fmaxf(acc[rt][ct][2] + bq.z, 0.f);
      v.h[3] = (_Float16)fmaxf(acc[rt][ct][3] + bq.w, 0.f);
      *(uint2*)&Hb[((kt2*4 + ct)*64 + lane2)*8 + j0] = v.u;
      acc[rt][ct] = zz;
    }
  }
  __syncthreads();

  // -------- layer 2: K=256 (8 k-tiles) --------
  __builtin_amdgcn_s_setprio(1);
  #pragma unroll 4
  for (int kt = 0; kt < 8; ++kt){
    f16x8 B[4];
    #pragma unroll
    for (int ct = 0; ct < 4; ++ct) B[ct] = *(f16x8*)&Hb[((kt*4 + ct)*64 + lane)*8];
    #pragma unroll
    for (int rt = 0; rt < 4; ++rt){
      f16x8 A = *(const f16x8*)&w2f[(((wr + rt)*8 + kt)*64 + lane)*8];
      #pragma unroll
      for (int ct = 0; ct < 4; ++ct)
        acc[rt][ct] = __builtin_amdgcn_mfma_f32_16x16x32_f16(A, B[ct], acc[rt][ct], 0, 0, 0);
    }
  }
  __builtin_amdgcn_s_setprio(0);
  __syncthreads();

  // -------- epilogue L2: bias+relu -> f16 fragment order (Bh2) --------
  #pragma unroll
  for (int rt = 0; rt < 4; ++rt){
    const int row0 = w*64 + rt*16 + ((lane >> 4) << 2);
    const float4 bq = *(const float4*)&b2[row0];
    const int kt2 = row0 >> 5, c16 = (row0 >> 3) & 3, j0 = row0 & 7;
    const int lane2 = (lane & 15) + c16*16;
    #pragma unroll
    for (int ct = 0; ct < 4; ++ct){
      H4 v;
      v.h[0] = (_Float16)fmaxf(acc[rt][ct][0] + bq.x, 0.f);
      v.h[1] = (_Float16)fmaxf(acc[rt][ct][1] + bq.y, 0.f);
      v.h[2] = (_Float16)fmaxf(acc[rt][ct][2] + bq.z, 0.f);
      v.h[3] = (_Float16)fmaxf(acc[rt][ct][3] + bq.w, 0.f);
      *(uint2*)&Hb[((kt2*4 + ct)*64 + lane2)*8 + j0] = v.u;
    }
  }
  __syncthreads();

  // -------- layer 3: rows 0..2, wave w handles col-tile w --------
  f32x4 a3 = zz;
  __builtin_amdgcn_s_setprio(1);
  #pragma unroll
  for (int kt = 0; kt < 8; ++kt){
    f16x8 B = *(f16x8*)&Hb[((kt*4 + w)*64 + lane)*8];
    f16x8 A = *(const f16x8*)&w3f[(kt*64 + lane)*8];
    a3 = __builtin_amdgcn_mfma_f32_16x16x32_f16(A, B, a3, 0, 0, 0);
  }
  __builtin_amdgcn_s_setprio(0);
  if (lane < 16){
    const float ox = a3[0] + b3[0];
    const float oy = a3[1] + b3[1];
    const float oz = a3[2] + b3[2];
    const float nrm = sqrtf(ox*ox + oy*oy + oz*oz);
    const float rg_ = fmaxf(nrm - (float)0.10825317547305482, 0.f);
    const int pt = w*16 + lane;
    const int cell = cells[pt];
    const float fx = ((float)(cell >> 8)        + 0.5f) * 0.0625f - 0.5f;
    const float fy = ((float)((cell >> 4) & 15) + 0.5f) * 0.0625f - 0.5f;
    const float fz = ((float)(cell & 15)        + 0.5f) * 0.0625f - 0.5f;
    const int pidx = p0 + pt;
    out[b*49152 +          pidx] = ox + fx;
    out[b*49152 + 16384 +  pidx] = oy + fy;
    out[b*49152 + 32768 +  pidx] = oz + fz;
    out[786432  + b*16384 + pidx] = rg_;
  }
}

extern "C" void kernel_launch(void* const* d_in, const int* in_sizes, int n_in,
                              void* d_out, int out_size, void* d_ws, size_t ws_size,
                              hipStream_t stream){
  const float* x     = (const float*)d_in[0];
  const float* dens  = (const float*)d_in[1];
  const float* noise = (const float*)d_in[2];
  const float* W1    = (const float*)d_in[3];
  const float* b1    = (const float*)d_in[4];
  const float* W2    = (const float*)d_in[5];
  const float* b2    = (const float*)d_in[6];
  const float* W3    = (const float*)d_in[7];
  const float* b3    = (const float*)d_in[8];

  char* ws = (char*)d_ws;
  int*      pc   = (int*)(ws + 0);
  _Float16* w1f  = (_Float16*)(ws + 1048576);
  _Float16* w2f  = (_Float16*)(ws + 1081344);
  _Float16* w3f  = (_Float16*)(ws + 1212416);
  float*    w1n  = (float*)(ws + 1220608);
  float*    out  = (float*)d_out;

  kP<<<dim3(59),      dim3(256), 0, stream>>>(dens, pc, W1, W2, W3, w1f, w2f, w3f, w1n);
  kE<<<dim3(256, 16), dim3(256), 0, stream>>>(x, noise, w1f, w2f, w3f, w1n,
                                              b1, b2, b3, pc, out);
}